// Round 9
// baseline (527.650 us; speedup 1.0000x reference)
//
#include <hip/hip_runtime.h>
#include <cstring>
#include <cstdint>

// Problem constants (fixed by reference)
#define B_TOTAL 8192
#define F_IN    1024
#define U_UNITS 256
#define NACT    16
#define HID     8

typedef float    f32x4  __attribute__((ext_vector_type(4)));
typedef _Float16 half8  __attribute__((ext_vector_type(8)));
typedef _Float16 half4  __attribute__((ext_vector_type(4)));

// ============================================================================
// MFMA path: fp16 split-2 emulation of fp32 GEMM (3 passes; 2 when A exact).
// Low parts pre-scaled by 2048 (fp16 normal range). Cross terms in acc2@2^-11.
//
// R9: back to R6's register-direct skeleton (every DMA/LDS-staged variant --
// R4/R5/R8 -- lost to it; SQ_LDS_BANK_CONFLICT 5.1e7 is intrinsic to
// global_load_lds's 16B/lane LDS-write pattern). New: software-pipelined
// K-loop. 64x64 dual-acc tile is locked at 2 waves/SIMD (128 acc AGPR + ~64
// frag VGPR), so latency must be hidden by ILP: kt+1's {Ah,Bh} loads issue
// after pass2 (bf/xa regs die there), {Al,Bl} after pass3 (af/xb die) ->
// next pass1 waits on loads issued ~32 MFMAs earlier instead of 0. Peak
// liveness ~= R6 (no spill, same occupancy). Per-tile acc chains keep exact
// R6 order => bit-identical absmax 0.21875. Packs fused into one launch.
// ============================================================================

// fp32 [R][K] -> packed high/low fp16 [R/16][K/32][64][8]; all three tensors
// in one launch (block ranges) to save inter-dispatch gaps.
__global__ __launch_bounds__(256)
void pack3_kernel(const float* __restrict__ s0, _Float16* __restrict__ d0h, _Float16* __restrict__ d0l,
                  const float* __restrict__ s1, _Float16* __restrict__ d1h, _Float16* __restrict__ d1l,
                  const float* __restrict__ s2, _Float16* __restrict__ d2h, _Float16* __restrict__ d2l)
{
    constexpr int NB0 = (B_TOTAL / 16) * (F_IN / 128);          // 4096
    constexpr int NB1 = (U_UNITS * HID / 16) * (F_IN / 128);    // 1024
    __shared__ float ls[16 * 132];
    int b = blockIdx.x;
    const float* src; _Float16 *dh, *dl; int K, lg;
    if (b < NB0)            { src = s0; dh = d0h; dl = d0l; K = F_IN;    lg = 3; }
    else if (b < NB0 + NB1) { b -= NB0; src = s1; dh = d1h; dl = d1l; K = F_IN; lg = 3; }
    else                    { b -= NB0 + NB1; src = s2; dh = d2h; dl = d2l; K = U_UNITS; lg = 1; }

    const int tid = threadIdx.x;
    const int mt  = b >> lg;               // 16-row tile
    const int kb  = b & ((1 << lg) - 1);   // 128-col slab
    const int r0  = mt * 16;

#pragma unroll
    for (int i = 0; i < 2; ++i) {
        const int e = tid + (i << 8);
        const int row = e >> 5;
        const int c4  = e & 31;
        f32x4 v = *reinterpret_cast<const f32x4*>(
            &src[(size_t)(r0 + row) * K + (kb << 7) + (c4 << 2)]);
        *reinterpret_cast<f32x4*>(&ls[row * 132 + (c4 << 2)]) = v;
    }
    __syncthreads();

    const int k8 = tid >> 4, r = tid & 15;
    float x[8];
#pragma unroll
    for (int j = 0; j < 8; ++j) x[j] = ls[r * 132 + (k8 << 3) + j];
    half8 h, l;
#pragma unroll
    for (int j = 0; j < 8; ++j) {
        h[j] = (_Float16)x[j];
        l[j] = (_Float16)((x[j] - (float)h[j]) * 2048.0f);
    }
    const size_t off = (((size_t)mt * (K >> 5)) + (kb << 2) + (k8 >> 2)) * 512
                     + (size_t)(((k8 & 3) << 4) + r) * 8;
    *reinterpret_cast<half8*>(&dh[off]) = h;
    *reinterpret_cast<half8*>(&dl[off]) = l;
}

constexpr int BM = 128, BN = 128;   // wave tile 64x64 (2x2 waves)

template<int K_TOTAL, bool A_SPLIT, bool OUT_TF32>
__global__ __launch_bounds__(256, 2)
void coagent_mfma(const _Float16* __restrict__ Ahg, const _Float16* __restrict__ Alg,
                  const _Float16* __restrict__ Bhg, const _Float16* __restrict__ Blg,
                  const float* __restrict__ b0, const float* __restrict__ W1,
                  const float* __restrict__ b1, const float* __restrict__ W2,
                  const float* __restrict__ b2, void* __restrict__ outp)
{
    struct EpiBufs { float Hs[BM][65]; _Float16 ab[BM * 8]; };
    __shared__ EpiBufs sm;

    constexpr int NTK = K_TOTAL >> 5;            // k-tiles (K=32 each)
    constexpr uint32_t TS = (uint32_t)NTK * 512; // halves per row-tile

    const int tid  = threadIdx.x;
    const int wave = tid >> 6;
    const int lane = tid & 63;
    const int quad = lane >> 4;
    const int l15  = lane & 15;
    const int wm   = (wave >> 1) * 64;
    const int m0   = blockIdx.y * BM;
    const int n0   = blockIdx.x * BN;

    const int at = (wave >> 1) * 4;
    const int bt = (wave & 1) * 4;

    uint32_t oA[4], oB[4];
#pragma unroll
    for (int mt = 0; mt < 4; ++mt)
        oA[mt] = (uint32_t)((m0 >> 4) + at + mt) * TS + (uint32_t)lane * 8;
#pragma unroll
    for (int nt = 0; nt < 4; ++nt)
        oB[nt] = (uint32_t)((n0 >> 4) + bt + nt) * TS + (uint32_t)lane * 8;

    f32x4 acc1[4][4];   // Ah*Bh            (scale 1)
    f32x4 acc2[4][4];   // Al'*Bh + Ah*Bl'  (scale 2^-11)
#pragma unroll
    for (int i = 0; i < 4; ++i)
#pragma unroll
        for (int j = 0; j < 4; ++j) { acc1[i][j] = {0.f,0.f,0.f,0.f}; acc2[i][j] = {0.f,0.f,0.f,0.f}; }

    // ---- prologue: load kt=0 fragments ----
    half8 af[4], bf[4], xa[4], xb[4];
#pragma unroll
    for (int mt = 0; mt < 4; ++mt) af[mt] = *reinterpret_cast<const half8*>(Ahg + oA[mt]);
#pragma unroll
    for (int nt = 0; nt < 4; ++nt) bf[nt] = *reinterpret_cast<const half8*>(Bhg + oB[nt]);
    if (A_SPLIT) {
#pragma unroll
        for (int mt = 0; mt < 4; ++mt) xa[mt] = *reinterpret_cast<const half8*>(Alg + oA[mt]);
    }
#pragma unroll
    for (int nt = 0; nt < 4; ++nt) xb[nt] = *reinterpret_cast<const half8*>(Blg + oB[nt]);

#pragma unroll 2
    for (int kt = 0; kt < NTK; ++kt) {
        const uint32_t ko = (uint32_t)(kt + 1) * 512;
        const bool more = (kt + 1 < NTK);
        half8 naf[4], nbf[4], nxa[4], nxb[4];

        // pass 1: Ah*Bh -> acc1
#pragma unroll
        for (int mt = 0; mt < 4; ++mt)
#pragma unroll
            for (int nt = 0; nt < 4; ++nt)
                acc1[mt][nt] = __builtin_amdgcn_mfma_f32_16x16x32_f16(af[mt], bf[nt], acc1[mt][nt], 0, 0, 0);
        // pass 2: Al'*Bh -> acc2
        if (A_SPLIT) {
#pragma unroll
            for (int mt = 0; mt < 4; ++mt)
#pragma unroll
                for (int nt = 0; nt < 4; ++nt)
                    acc2[mt][nt] = __builtin_amdgcn_mfma_f32_16x16x32_f16(xa[mt], bf[nt], acc2[mt][nt], 0, 0, 0);
        }
        // bf/xa are dead now: issue kt+1 highs (32 regs of headroom)
        if (more) {
#pragma unroll
            for (int mt = 0; mt < 4; ++mt) naf[mt] = *reinterpret_cast<const half8*>(Ahg + oA[mt] + ko);
#pragma unroll
            for (int nt = 0; nt < 4; ++nt) nbf[nt] = *reinterpret_cast<const half8*>(Bhg + oB[nt] + ko);
        }
        // pass 3: Ah*Bl' -> acc2
#pragma unroll
        for (int mt = 0; mt < 4; ++mt)
#pragma unroll
            for (int nt = 0; nt < 4; ++nt)
                acc2[mt][nt] = __builtin_amdgcn_mfma_f32_16x16x32_f16(af[mt], xb[nt], acc2[mt][nt], 0, 0, 0);
        // af/xb dead: issue kt+1 lows, rotate
        if (more) {
            if (A_SPLIT) {
#pragma unroll
                for (int mt = 0; mt < 4; ++mt) nxa[mt] = *reinterpret_cast<const half8*>(Alg + oA[mt] + ko);
            }
#pragma unroll
            for (int nt = 0; nt < 4; ++nt) nxb[nt] = *reinterpret_cast<const half8*>(Blg + oB[nt] + ko);
#pragma unroll
            for (int i = 0; i < 4; ++i) {
                af[i] = naf[i]; bf[i] = nbf[i];
                if (A_SPLIT) xa[i] = nxa[i];
                xb[i] = nxb[i];
            }
        }
    }

    // ---- epilogue: two 64-col halves (8 units each) ----
    const int ubase = n0 >> 3;
    for (int half = 0; half < 2; ++half) {
        __syncthreads();
        if ((wave & 1) == half) {
#pragma unroll
            for (int mt = 0; mt < 4; ++mt)
#pragma unroll
                for (int nt = 0; nt < 4; ++nt)
#pragma unroll
                    for (int r = 0; r < 4; ++r)
                        sm.Hs[wm + mt * 16 + quad * 4 + r][nt * 16 + l15] =
                            acc1[mt][nt][r] + acc2[mt][nt][r] * (1.0f / 2048.0f);
        }
        __syncthreads();
#pragma unroll
        for (int p = 0; p < 4; ++p) {
            const int pair = (p << 8) + tid;
            const int ul = pair >> 7;           // wave-uniform
            const int bl = pair & 127;          // lane-consecutive
            const int u  = ubase + half * 8 + ul;

            float h[HID];
#pragma unroll
            for (int j = 0; j < HID; ++j)
                h[j] = fmaxf(sm.Hs[bl][ul * 8 + j] + b0[u * 8 + j], 0.f);

            float h2[HID];
#pragma unroll
            for (int g = 0; g < HID; ++g) {
                float s = b1[u * 8 + g];
#pragma unroll
                for (int j = 0; j < HID; ++j)
                    s += h[j] * W1[u * 64 + g * 8 + j];
                h2[g] = fmaxf(s, 0.f);
            }

            float best = b2[u * 16];
#pragma unroll
            for (int j = 0; j < HID; ++j) best += h2[j] * W2[u * 128 + j];
            int bi = 0;
#pragma unroll
            for (int a = 1; a < NACT; ++a) {
                float s = b2[u * 16 + a];
#pragma unroll
                for (int j = 0; j < HID; ++j)
                    s += h2[j] * W2[u * 128 + a * 8 + j];
                if (s > best) { best = s; bi = a; }   // first-max-wins = np.argmax
            }

            if (OUT_TF32) {
                ((float*)outp)[(size_t)u * B_TOTAL + m0 + bl] = (float)bi;
            } else {
                sm.ab[bl * 8 + ul] = (_Float16)bi;
            }
        }
        if (!OUT_TF32) {
            __syncthreads();
            if (tid < 128) {   // write a0 in PACKED layout (NTK=8 for K=256)
                float4 v = *reinterpret_cast<float4*>(&sm.ab[tid * 8]);
                const int u = ubase + half * 8;          // octet base, uniform
                const int b = m0 + tid;
                const size_t off = ((size_t)(b >> 4) * 8 + (u >> 5)) * 512
                                 + (size_t)((((u >> 3) & 3) << 4) + (b & 15)) * 8;
                *reinterpret_cast<float4*>(&((_Float16*)outp)[off]) = v;
            }
        }
    }
}

// ============================================================================
// fp32 fallback path (round-1 kernels) — used only if ws_size is too small
// ============================================================================

constexpr int FBM = 128, FBN = 128, FBK = 16;

template<int K_TOTAL, bool X_TRANSPOSED>
__global__ __launch_bounds__(256, 2)
void coagent_kernel(const float* __restrict__ X, const float* __restrict__ W0,
                    const float* __restrict__ b0, const float* __restrict__ W1,
                    const float* __restrict__ b1, const float* __restrict__ W2,
                    const float* __restrict__ b2, float* __restrict__ outT)
{
    struct SMemGemm { float As[FBK][FBM + 4]; float Bs[FBK][FBN + 4]; };
    union SMem { SMemGemm g; float Hs[FBM][65]; };
    __shared__ SMem sm;

    const int tid = threadIdx.x;
    const int tx = tid & 15, ty = tid >> 4;
    const int m0 = blockIdx.y * FBM, n0 = blockIdx.x * FBN;

    float acc[8][8];
#pragma unroll
    for (int i = 0; i < 8; ++i)
#pragma unroll
        for (int j = 0; j < 8; ++j) acc[i][j] = 0.f;

    for (int k0 = 0; k0 < K_TOTAL; k0 += FBK) {
        __syncthreads();
        if (X_TRANSPOSED) {
#pragma unroll
            for (int l = tid; l < (FBM * FBK) / 4; l += 256) {
                const int k = l >> 5, q = l & 31;
                const float4 v = *reinterpret_cast<const float4*>(
                    &X[(size_t)(k0 + k) * B_TOTAL + m0 + 4 * q]);
                *reinterpret_cast<float4*>(&sm.g.As[k][4 * q]) = v;
            }
        } else {
#pragma unroll
            for (int l = tid; l < (FBM * FBK) / 4; l += 256) {
                const int row = l >> 2, c = l & 3;
                const float4 v = *reinterpret_cast<const float4*>(
                    &X[(size_t)(m0 + row) * K_TOTAL + k0 + 4 * c]);
                sm.g.As[4 * c + 0][row] = v.x; sm.g.As[4 * c + 1][row] = v.y;
                sm.g.As[4 * c + 2][row] = v.z; sm.g.As[4 * c + 3][row] = v.w;
            }
        }
#pragma unroll
        for (int l = tid; l < (FBN * FBK) / 4; l += 256) {
            const int row = l >> 2, c = l & 3;
            const float4 v = *reinterpret_cast<const float4*>(
                &W0[(size_t)(n0 + row) * K_TOTAL + k0 + 4 * c]);
            sm.g.Bs[4 * c + 0][row] = v.x; sm.g.Bs[4 * c + 1][row] = v.y;
            sm.g.Bs[4 * c + 2][row] = v.z; sm.g.Bs[4 * c + 3][row] = v.w;
        }
        __syncthreads();
#pragma unroll
        for (int k = 0; k < FBK; ++k) {
            float a[8], bb[8];
            *reinterpret_cast<float4*>(&a[0])  = *reinterpret_cast<float4*>(&sm.g.As[k][4 * ty]);
            *reinterpret_cast<float4*>(&a[4])  = *reinterpret_cast<float4*>(&sm.g.As[k][64 + 4 * ty]);
            *reinterpret_cast<float4*>(&bb[0]) = *reinterpret_cast<float4*>(&sm.g.Bs[k][4 * tx]);
            *reinterpret_cast<float4*>(&bb[4]) = *reinterpret_cast<float4*>(&sm.g.Bs[k][64 + 4 * tx]);
#pragma unroll
            for (int i = 0; i < 8; ++i)
#pragma unroll
                for (int j = 0; j < 8; ++j) acc[i][j] += a[i] * bb[j];
        }
    }

    const int ub_base = n0 >> 3;
    for (int half = 0; half < 2; ++half) {
        __syncthreads();
#pragma unroll
        for (int i = 0; i < 8; ++i) {
            const int row = (i < 4) ? (4 * ty + i) : (64 + 4 * ty + (i - 4));
#pragma unroll
            for (int j = 0; j < 4; ++j)
                sm.Hs[row][4 * tx + j] = acc[i][4 * half + j];
        }
        __syncthreads();
#pragma unroll
        for (int p = 0; p < 4; ++p) {
            const int pair = (p << 8) + tid;
            const int ul = pair >> 7, bl = pair & 127;
            const int u = ub_base + half * 8 + ul;
            float h[HID];
#pragma unroll
            for (int j = 0; j < HID; ++j)
                h[j] = fmaxf(sm.Hs[bl][ul * 8 + j] + b0[u * 8 + j], 0.f);
            float h2[HID];
#pragma unroll
            for (int g = 0; g < HID; ++g) {
                float s = b1[u * 8 + g];
#pragma unroll
                for (int j = 0; j < HID; ++j) s += h[j] * W1[u * 64 + g * 8 + j];
                h2[g] = fmaxf(s, 0.f);
            }
            float best = b2[u * 16];
#pragma unroll
            for (int j = 0; j < HID; ++j) best += h2[j] * W2[u * 128 + j];
            int bi = 0;
#pragma unroll
            for (int a = 1; a < NACT; ++a) {
                float s = b2[u * 16 + a];
#pragma unroll
                for (int j = 0; j < HID; ++j) s += h2[j] * W2[u * 128 + a * 8 + j];
                if (s > best) { best = s; bi = a; }
            }
            outT[(size_t)u * B_TOTAL + m0 + bl] = (float)bi;
        }
    }
}

// Policy head (reads a1T fp32 [U][B], coalesced across lanes; u-loop unrolled
// x8 so 8 loads are in flight instead of a 256-deep serial latency chain)
__global__ __launch_bounds__(256)
void policy_kernel(const float* __restrict__ A1T,
                   const float* __restrict__ PW0, const float* __restrict__ Pb0,
                   const float* __restrict__ PW1, const float* __restrict__ Pb1,
                   const float* __restrict__ PW2, const float* __restrict__ Pb2,
                   float* __restrict__ out)
{
    const int b = blockIdx.x * blockDim.x + threadIdx.x;
    if (b >= B_TOTAL) return;
    float hp[HID];
#pragma unroll
    for (int j = 0; j < HID; ++j) hp[j] = Pb0[j];
    for (int u0 = 0; u0 < U_UNITS; u0 += 8) {
        float v[8];
#pragma unroll
        for (int q = 0; q < 8; ++q)
            v[q] = A1T[(size_t)(u0 + q) * B_TOTAL + b];
#pragma unroll
        for (int q = 0; q < 8; ++q)
#pragma unroll
            for (int j = 0; j < HID; ++j)
                hp[j] += v[q] * PW0[j * U_UNITS + u0 + q];
    }
    float h[HID];
#pragma unroll
    for (int j = 0; j < HID; ++j) h[j] = fmaxf(hp[j], 0.f);
    float h2[HID];
#pragma unroll
    for (int g = 0; g < HID; ++g) {
        float s = Pb1[g];
#pragma unroll
        for (int j = 0; j < HID; ++j) s += h[j] * PW1[g * 8 + j];
        h2[g] = fmaxf(s, 0.f);
    }
    float o = Pb2[0];
#pragma unroll
    for (int j = 0; j < HID; ++j) o += h2[j] * PW2[j];
    out[b] = o;
}

// ============================================================================

extern "C" void kernel_launch(void* const* d_in, const int* in_sizes, int n_in,
                              void* d_out, int out_size, void* d_ws, size_t ws_size,
                              hipStream_t stream)
{
    const float* state = (const float*)d_in[0];
    const float* W0_0  = (const float*)d_in[1];
    const float* b0_0  = (const float*)d_in[2];
    const float* W1_0  = (const float*)d_in[3];
    const float* b1_0  = (const float*)d_in[4];
    const float* W2_0  = (const float*)d_in[5];
    const float* b2_0  = (const float*)d_in[6];
    const float* W0_1  = (const float*)d_in[7];
    const float* b0_1  = (const float*)d_in[8];
    const float* W1_1  = (const float*)d_in[9];
    const float* b1_1  = (const float*)d_in[10];
    const float* W2_1  = (const float*)d_in[11];
    const float* b2_1  = (const float*)d_in[12];
    const float* PW0   = (const float*)d_in[13];
    const float* Pb0   = (const float*)d_in[14];
    const float* PW1   = (const float*)d_in[15];
    const float* Pb1   = (const float*)d_in[16];
    const float* PW2   = (const float*)d_in[17];
    const float* Pb2   = (const float*)d_in[18];

    // ws layout (elements)
    const size_t SZ_STATE = (size_t)B_TOTAL * F_IN;
    const size_t SZ_W00   = (size_t)U_UNITS * HID * F_IN;
    const size_t SZ_W01   = (size_t)U_UNITS * HID * U_UNITS;
    const size_t NEED = (2 * SZ_STATE + 2 * SZ_W00 + 2 * SZ_W01
                         + (size_t)B_TOTAL * U_UNITS) * 2            // fp16 parts + a0
                        + (size_t)U_UNITS * B_TOTAL * 4;             // a1T fp32

    if (ws_size >= NEED) {
        char* p = (char*)d_ws;
        _Float16* state_h = (_Float16*)p;                p += SZ_STATE * 2;
        _Float16* state_l = (_Float16*)p;                p += SZ_STATE * 2;
        _Float16* w00_h   = (_Float16*)p;                p += SZ_W00 * 2;
        _Float16* w00_l   = (_Float16*)p;                p += SZ_W00 * 2;
        _Float16* w01_h   = (_Float16*)p;                p += SZ_W01 * 2;
        _Float16* w01_l   = (_Float16*)p;                p += SZ_W01 * 2;
        _Float16* a0      = (_Float16*)p;                p += (size_t)B_TOTAL * U_UNITS * 2;
        float*    a1T     = (float*)p;

        // fused pack: fp32 -> fragment-ordered fp16 (h, l*2048), one launch
        constexpr int NB0 = (B_TOTAL / 16) * (F_IN / 128);
        constexpr int NB1 = (U_UNITS * HID / 16) * (F_IN / 128);
        constexpr int NB2 = (U_UNITS * HID / 16) * (U_UNITS / 128);
        pack3_kernel<<<NB0 + NB1 + NB2, 256, 0, stream>>>(
            state, state_h, state_l, W0_0, w00_h, w00_l, W0_1, w01_h, w01_l);

        dim3 grid((U_UNITS * HID) / BN, B_TOTAL / BM);   // (16, 64)

        coagent_mfma<F_IN, true, false><<<grid, 256, 0, stream>>>(
            state_h, state_l, w00_h, w00_l, b0_0, W1_0, b1_0, W2_0, b2_0, (void*)a0);

        coagent_mfma<U_UNITS, false, true><<<grid, 256, 0, stream>>>(
            a0, nullptr, w01_h, w01_l, b0_1, W1_1, b1_1, W2_1, b2_1, (void*)a1T);

        policy_kernel<<<B_TOTAL / 256, 256, 0, stream>>>(
            a1T, PW0, Pb0, PW1, Pb1, PW2, Pb2, (float*)d_out);
    } else {
        // fp32 fallback (round-1 path, needs 16 MB ws)
        float* a0T = (float*)d_ws;
        float* a1T = a0T + (size_t)U_UNITS * B_TOTAL;
        dim3 grid((U_UNITS * HID) / FBN, B_TOTAL / FBM);
        coagent_kernel<F_IN, false><<<grid, 256, 0, stream>>>(
            state, W0_0, b0_0, W1_0, b1_0, W2_0, b2_0, a0T);
        coagent_kernel<U_UNITS, true><<<grid, 256, 0, stream>>>(
            a0T, W0_1, b0_1, W1_1, b1_1, W2_1, b2_1, a1T);
        policy_kernel<<<B_TOTAL / 256, 256, 0, stream>>>(
            a1T, PW0, Pb0, PW1, Pb1, PW2, Pb2, (float*)d_out);
    }
}

// Round 10
// 320.840 us; speedup vs baseline: 1.6446x; 1.6446x over previous
//
#include <hip/hip_runtime.h>
#include <cstring>
#include <cstdint>

// Problem constants (fixed by reference)
#define B_TOTAL 8192
#define F_IN    1024
#define U_UNITS 256
#define NACT    16
#define HID     8

typedef float    f32x4  __attribute__((ext_vector_type(4)));
typedef _Float16 half8  __attribute__((ext_vector_type(8)));
typedef _Float16 half4  __attribute__((ext_vector_type(4)));

// ============================================================================
// MFMA path: fp16 split-2 emulation of fp32 GEMM (3 passes; 2 when A exact).
// Low parts pre-scaled by 2048 (fp16 normal range). Cross terms in acc2@2^-11.
//
// R10: K-loop is EXACTLY R6's (register-direct, 64x64 wave tile, loads up
// front each kt). R7/R8/R9 all lost to it (R9 spilled: dual fragment sets +
// 128 acc AGPRs > 256 regs -> 480 MB scratch WRITE_SIZE). New in R10:
//  * epilogue per-unit weights accessed via readfirstlane-pinned uniform
//    pointers -> scalar (SMEM) loads instead of ~1792 vector loads per wave.
//    Values identical => bit-identical output (absmax 0.21875).
//  * policy head parallelized 32 -> 256 blocks (u-sliced, LDS reduce; final
//    layer, no argmax downstream, reassociation harmless).
// ============================================================================

// fp32 [R][K] -> packed high/low fp16 [R/16][K/32][64][8]; all three tensors
// in one launch (block ranges) to save inter-dispatch gaps.
__global__ __launch_bounds__(256)
void pack3_kernel(const float* __restrict__ s0, _Float16* __restrict__ d0h, _Float16* __restrict__ d0l,
                  const float* __restrict__ s1, _Float16* __restrict__ d1h, _Float16* __restrict__ d1l,
                  const float* __restrict__ s2, _Float16* __restrict__ d2h, _Float16* __restrict__ d2l)
{
    constexpr int NB0 = (B_TOTAL / 16) * (F_IN / 128);          // 4096
    constexpr int NB1 = (U_UNITS * HID / 16) * (F_IN / 128);    // 1024
    __shared__ float ls[16 * 132];
    int b = blockIdx.x;
    const float* src; _Float16 *dh, *dl; int K, lg;
    if (b < NB0)            { src = s0; dh = d0h; dl = d0l; K = F_IN;    lg = 3; }
    else if (b < NB0 + NB1) { b -= NB0; src = s1; dh = d1h; dl = d1l; K = F_IN; lg = 3; }
    else                    { b -= NB0 + NB1; src = s2; dh = d2h; dl = d2l; K = U_UNITS; lg = 1; }

    const int tid = threadIdx.x;
    const int mt  = b >> lg;
    const int kb  = b & ((1 << lg) - 1);
    const int r0  = mt * 16;

#pragma unroll
    for (int i = 0; i < 2; ++i) {
        const int e = tid + (i << 8);
        const int row = e >> 5;
        const int c4  = e & 31;
        f32x4 v = *reinterpret_cast<const f32x4*>(
            &src[(size_t)(r0 + row) * K + (kb << 7) + (c4 << 2)]);
        *reinterpret_cast<f32x4*>(&ls[row * 132 + (c4 << 2)]) = v;
    }
    __syncthreads();

    const int k8 = tid >> 4, r = tid & 15;
    float x[8];
#pragma unroll
    for (int j = 0; j < 8; ++j) x[j] = ls[r * 132 + (k8 << 3) + j];
    half8 h, l;
#pragma unroll
    for (int j = 0; j < 8; ++j) {
        h[j] = (_Float16)x[j];
        l[j] = (_Float16)((x[j] - (float)h[j]) * 2048.0f);
    }
    const size_t off = (((size_t)mt * (K >> 5)) + (kb << 2) + (k8 >> 2)) * 512
                     + (size_t)(((k8 & 3) << 4) + r) * 8;
    *reinterpret_cast<half8*>(&dh[off]) = h;
    *reinterpret_cast<half8*>(&dl[off]) = l;
}

constexpr int BM = 128, BN = 128;   // wave tile 64x64 (2x2 waves)

template<int K_TOTAL, bool A_SPLIT, bool OUT_TF32>
__global__ __launch_bounds__(256, 2)
void coagent_mfma(const _Float16* __restrict__ Ahg, const _Float16* __restrict__ Alg,
                  const _Float16* __restrict__ Bhg, const _Float16* __restrict__ Blg,
                  const float* __restrict__ b0, const float* __restrict__ W1,
                  const float* __restrict__ b1, const float* __restrict__ W2,
                  const float* __restrict__ b2, void* __restrict__ outp)
{
    struct EpiBufs { float Hs[BM][65]; _Float16 ab[BM * 8]; };
    __shared__ EpiBufs sm;

    constexpr int NTK = K_TOTAL >> 5;        // k-tiles (K=32 each)
    constexpr size_t TS = (size_t)NTK * 512; // halves per row-tile

    const int tid  = threadIdx.x;
    const int wave = tid >> 6;
    const int lane = tid & 63;
    const int quad = lane >> 4;
    const int l15  = lane & 15;
    const int wm   = (wave >> 1) * 64;
    const int m0   = blockIdx.y * BM;
    const int n0   = blockIdx.x * BN;

    const int at = (wave >> 1) * 4;
    const int bt = (wave & 1) * 4;

    // per-lane fragment base pointers (lane-contiguous 16B chunks)
    const _Float16* Ah0 = Ahg + ((size_t)((m0 >> 4) + at)) * TS + lane * 8;
    const _Float16* Al0 = A_SPLIT ? (Alg + ((size_t)((m0 >> 4) + at)) * TS + lane * 8) : nullptr;
    const _Float16* Bh0 = Bhg + ((size_t)((n0 >> 4) + bt)) * TS + lane * 8;
    const _Float16* Bl0 = Blg + ((size_t)((n0 >> 4) + bt)) * TS + lane * 8;

    f32x4 acc1[4][4];   // Ah*Bh            (scale 1)
    f32x4 acc2[4][4];   // Al'*Bh + Ah*Bl'  (scale 2^-11)
#pragma unroll
    for (int i = 0; i < 4; ++i)
#pragma unroll
        for (int j = 0; j < 4; ++j) { acc1[i][j] = {0.f,0.f,0.f,0.f}; acc2[i][j] = {0.f,0.f,0.f,0.f}; }

    for (int kt = 0; kt < NTK; ++kt) {
        const size_t ko = (size_t)kt * 512;
        half8 af[4], bf[4], xa[4], xb[4];
        // issue all fragment loads up front (highs first)
#pragma unroll
        for (int mt = 0; mt < 4; ++mt)
            af[mt] = *reinterpret_cast<const half8*>(Ah0 + mt * TS + ko);
#pragma unroll
        for (int nt = 0; nt < 4; ++nt)
            bf[nt] = *reinterpret_cast<const half8*>(Bh0 + nt * TS + ko);
        if (A_SPLIT) {
#pragma unroll
            for (int mt = 0; mt < 4; ++mt)
                xa[mt] = *reinterpret_cast<const half8*>(Al0 + mt * TS + ko);
        }
#pragma unroll
        for (int nt = 0; nt < 4; ++nt)
            xb[nt] = *reinterpret_cast<const half8*>(Bl0 + nt * TS + ko);

        // pass 1: Ah*Bh -> acc1
#pragma unroll
        for (int mt = 0; mt < 4; ++mt)
#pragma unroll
            for (int nt = 0; nt < 4; ++nt)
                acc1[mt][nt] = __builtin_amdgcn_mfma_f32_16x16x32_f16(af[mt], bf[nt], acc1[mt][nt], 0, 0, 0);
        // pass 2: Al'*Bh -> acc2
        if (A_SPLIT) {
#pragma unroll
            for (int mt = 0; mt < 4; ++mt)
#pragma unroll
                for (int nt = 0; nt < 4; ++nt)
                    acc2[mt][nt] = __builtin_amdgcn_mfma_f32_16x16x32_f16(xa[mt], bf[nt], acc2[mt][nt], 0, 0, 0);
        }
        // pass 3: Ah*Bl' -> acc2
#pragma unroll
        for (int mt = 0; mt < 4; ++mt)
#pragma unroll
            for (int nt = 0; nt < 4; ++nt)
                acc2[mt][nt] = __builtin_amdgcn_mfma_f32_16x16x32_f16(af[mt], xb[nt], acc2[mt][nt], 0, 0, 0);
    }

    // ---- epilogue: two 64-col halves (8 units each) ----
    const int ubase = n0 >> 3;
    for (int half = 0; half < 2; ++half) {
        __syncthreads();
        if ((wave & 1) == half) {
#pragma unroll
            for (int mt = 0; mt < 4; ++mt)
#pragma unroll
                for (int nt = 0; nt < 4; ++nt)
#pragma unroll
                    for (int r = 0; r < 4; ++r)
                        sm.Hs[wm + mt * 16 + quad * 4 + r][nt * 16 + l15] =
                            acc1[mt][nt][r] + acc2[mt][nt][r] * (1.0f / 2048.0f);
        }
        __syncthreads();
#pragma unroll
        for (int p = 0; p < 4; ++p) {
            const int pair = (p << 8) + tid;
            const int ul = pair >> 7;           // wave-uniform
            const int bl = pair & 127;          // lane-consecutive
            // pin u as wave-uniform -> weight loads become scalar (SMEM pipe)
            const int u  = __builtin_amdgcn_readfirstlane(ubase + half * 8 + ul);
            const float* __restrict__ b0u = b0 + u * 8;
            const float* __restrict__ W1u = W1 + u * 64;
            const float* __restrict__ b1u = b1 + u * 8;
            const float* __restrict__ W2u = W2 + u * 128;
            const float* __restrict__ b2u = b2 + u * 16;

            float h[HID];
#pragma unroll
            for (int j = 0; j < HID; ++j)
                h[j] = fmaxf(sm.Hs[bl][ul * 8 + j] + b0u[j], 0.f);

            float h2[HID];
#pragma unroll
            for (int g = 0; g < HID; ++g) {
                float s = b1u[g];
#pragma unroll
                for (int j = 0; j < HID; ++j)
                    s += h[j] * W1u[g * 8 + j];
                h2[g] = fmaxf(s, 0.f);
            }

            float best = b2u[0];
#pragma unroll
            for (int j = 0; j < HID; ++j) best += h2[j] * W2u[j];
            int bi = 0;
#pragma unroll
            for (int a = 1; a < NACT; ++a) {
                float s = b2u[a];
#pragma unroll
                for (int j = 0; j < HID; ++j)
                    s += h2[j] * W2u[a * 8 + j];
                if (s > best) { best = s; bi = a; }   // first-max-wins = np.argmax
            }

            if (OUT_TF32) {
                ((float*)outp)[(size_t)u * B_TOTAL + m0 + bl] = (float)bi;
            } else {
                sm.ab[bl * 8 + ul] = (_Float16)bi;
            }
        }
        if (!OUT_TF32) {
            __syncthreads();
            if (tid < 128) {   // write a0 in PACKED layout (NTK=8 for K=256)
                float4 v = *reinterpret_cast<float4*>(&sm.ab[tid * 8]);
                const int u = ubase + half * 8;          // octet base, uniform
                const int b = m0 + tid;
                const size_t off = ((size_t)(b >> 4) * 8 + (u >> 5)) * 512
                                 + (size_t)((((u >> 3) & 3) << 4) + (b & 15)) * 8;
                *reinterpret_cast<float4*>(&((_Float16*)outp)[off]) = v;
            }
        }
    }
}

// ============================================================================
// fp32 fallback path (round-1 kernels) — used only if ws_size is too small
// ============================================================================

constexpr int FBM = 128, FBN = 128, FBK = 16;

template<int K_TOTAL, bool X_TRANSPOSED>
__global__ __launch_bounds__(256, 2)
void coagent_kernel(const float* __restrict__ X, const float* __restrict__ W0,
                    const float* __restrict__ b0, const float* __restrict__ W1,
                    const float* __restrict__ b1, const float* __restrict__ W2,
                    const float* __restrict__ b2, float* __restrict__ outT)
{
    struct SMemGemm { float As[FBK][FBM + 4]; float Bs[FBK][FBN + 4]; };
    union SMem { SMemGemm g; float Hs[FBM][65]; };
    __shared__ SMem sm;

    const int tid = threadIdx.x;
    const int tx = tid & 15, ty = tid >> 4;
    const int m0 = blockIdx.y * FBM, n0 = blockIdx.x * FBN;

    float acc[8][8];
#pragma unroll
    for (int i = 0; i < 8; ++i)
#pragma unroll
        for (int j = 0; j < 8; ++j) acc[i][j] = 0.f;

    for (int k0 = 0; k0 < K_TOTAL; k0 += FBK) {
        __syncthreads();
        if (X_TRANSPOSED) {
#pragma unroll
            for (int l = tid; l < (FBM * FBK) / 4; l += 256) {
                const int k = l >> 5, q = l & 31;
                const float4 v = *reinterpret_cast<const float4*>(
                    &X[(size_t)(k0 + k) * B_TOTAL + m0 + 4 * q]);
                *reinterpret_cast<float4*>(&sm.g.As[k][4 * q]) = v;
            }
        } else {
#pragma unroll
            for (int l = tid; l < (FBM * FBK) / 4; l += 256) {
                const int row = l >> 2, c = l & 3;
                const float4 v = *reinterpret_cast<const float4*>(
                    &X[(size_t)(m0 + row) * K_TOTAL + k0 + 4 * c]);
                sm.g.As[4 * c + 0][row] = v.x; sm.g.As[4 * c + 1][row] = v.y;
                sm.g.As[4 * c + 2][row] = v.z; sm.g.As[4 * c + 3][row] = v.w;
            }
        }
#pragma unroll
        for (int l = tid; l < (FBN * FBK) / 4; l += 256) {
            const int row = l >> 2, c = l & 3;
            const float4 v = *reinterpret_cast<const float4*>(
                &W0[(size_t)(n0 + row) * K_TOTAL + k0 + 4 * c]);
            sm.g.Bs[4 * c + 0][row] = v.x; sm.g.Bs[4 * c + 1][row] = v.y;
            sm.g.Bs[4 * c + 2][row] = v.z; sm.g.Bs[4 * c + 3][row] = v.w;
        }
        __syncthreads();
#pragma unroll
        for (int k = 0; k < FBK; ++k) {
            float a[8], bb[8];
            *reinterpret_cast<float4*>(&a[0])  = *reinterpret_cast<float4*>(&sm.g.As[k][4 * ty]);
            *reinterpret_cast<float4*>(&a[4])  = *reinterpret_cast<float4*>(&sm.g.As[k][64 + 4 * ty]);
            *reinterpret_cast<float4*>(&bb[0]) = *reinterpret_cast<float4*>(&sm.g.Bs[k][4 * tx]);
            *reinterpret_cast<float4*>(&bb[4]) = *reinterpret_cast<float4*>(&sm.g.Bs[k][64 + 4 * tx]);
#pragma unroll
            for (int i = 0; i < 8; ++i)
#pragma unroll
                for (int j = 0; j < 8; ++j) acc[i][j] += a[i] * bb[j];
        }
    }

    const int ub_base = n0 >> 3;
    for (int half = 0; half < 2; ++half) {
        __syncthreads();
#pragma unroll
        for (int i = 0; i < 8; ++i) {
            const int row = (i < 4) ? (4 * ty + i) : (64 + 4 * ty + (i - 4));
#pragma unroll
            for (int j = 0; j < 4; ++j)
                sm.Hs[row][4 * tx + j] = acc[i][4 * half + j];
        }
        __syncthreads();
#pragma unroll
        for (int p = 0; p < 4; ++p) {
            const int pair = (p << 8) + tid;
            const int ul = pair >> 7, bl = pair & 127;
            const int u = ub_base + half * 8 + ul;
            float h[HID];
#pragma unroll
            for (int j = 0; j < HID; ++j)
                h[j] = fmaxf(sm.Hs[bl][ul * 8 + j] + b0[u * 8 + j], 0.f);
            float h2[HID];
#pragma unroll
            for (int g = 0; g < HID; ++g) {
                float s = b1[u * 8 + g];
#pragma unroll
                for (int j = 0; j < HID; ++j) s += h[j] * W1[u * 64 + g * 8 + j];
                h2[g] = fmaxf(s, 0.f);
            }
            float best = b2[u * 16];
#pragma unroll
            for (int j = 0; j < HID; ++j) best += h2[j] * W2[u * 128 + j];
            int bi = 0;
#pragma unroll
            for (int a = 1; a < NACT; ++a) {
                float s = b2[u * 16 + a];
#pragma unroll
                for (int j = 0; j < HID; ++j) s += h2[j] * W2[u * 128 + a * 8 + j];
                if (s > best) { best = s; bi = a; }
            }
            outT[(size_t)u * B_TOTAL + m0 + bl] = (float)bi;
        }
    }
}

// Policy head, u-sliced: 256 blocks x 256 thr; block = 32 batch rows,
// 8 slices x 32 units each, LDS reduce. Final layer (no argmax downstream):
// reassociating the u-sum is harmless (~1e-5 on output, threshold 0.27).
__global__ __launch_bounds__(256)
void policy_kernel(const float* __restrict__ A1T,
                   const float* __restrict__ PW0, const float* __restrict__ Pb0,
                   const float* __restrict__ PW1, const float* __restrict__ Pb1,
                   const float* __restrict__ PW2, const float* __restrict__ Pb2,
                   float* __restrict__ out)
{
    __shared__ float part[8][32][HID + 1];
    const int tid = threadIdx.x;
    const int b32 = tid & 31;          // local batch row
    const int sl  = tid >> 5;          // u-slice 0..7
    const int b   = blockIdx.x * 32 + b32;

    float hp[HID];
#pragma unroll
    for (int j = 0; j < HID; ++j) hp[j] = 0.f;

#pragma unroll 1
    for (int q0 = 0; q0 < 32; q0 += 8) {
        float v[8];
#pragma unroll
        for (int t = 0; t < 8; ++t)
            v[t] = A1T[(size_t)(sl * 32 + q0 + t) * B_TOTAL + b];
#pragma unroll
        for (int t = 0; t < 8; ++t)
#pragma unroll
            for (int j = 0; j < HID; ++j)
                hp[j] += v[t] * PW0[j * U_UNITS + sl * 32 + q0 + t];
    }
#pragma unroll
    for (int j = 0; j < HID; ++j) part[sl][b32][j] = hp[j];
    __syncthreads();

    if (sl == 0) {
        float h[HID];
#pragma unroll
        for (int j = 0; j < HID; ++j) {
            float s = Pb0[j];
#pragma unroll
            for (int s8 = 0; s8 < 8; ++s8) s += part[s8][b32][j];
            h[j] = fmaxf(s, 0.f);
        }
        float h2[HID];
#pragma unroll
        for (int g = 0; g < HID; ++g) {
            float s = Pb1[g];
#pragma unroll
            for (int j = 0; j < HID; ++j) s += h[j] * PW1[g * 8 + j];
            h2[g] = fmaxf(s, 0.f);
        }
        float o = Pb2[0];
#pragma unroll
        for (int j = 0; j < HID; ++j) o += h2[j] * PW2[j];
        out[b] = o;
    }
}

// ============================================================================

extern "C" void kernel_launch(void* const* d_in, const int* in_sizes, int n_in,
                              void* d_out, int out_size, void* d_ws, size_t ws_size,
                              hipStream_t stream)
{
    const float* state = (const float*)d_in[0];
    const float* W0_0  = (const float*)d_in[1];
    const float* b0_0  = (const float*)d_in[2];
    const float* W1_0  = (const float*)d_in[3];
    const float* b1_0  = (const float*)d_in[4];
    const float* W2_0  = (const float*)d_in[5];
    const float* b2_0  = (const float*)d_in[6];
    const float* W0_1  = (const float*)d_in[7];
    const float* b0_1  = (const float*)d_in[8];
    const float* W1_1  = (const float*)d_in[9];
    const float* b1_1  = (const float*)d_in[10];
    const float* W2_1  = (const float*)d_in[11];
    const float* b2_1  = (const float*)d_in[12];
    const float* PW0   = (const float*)d_in[13];
    const float* Pb0   = (const float*)d_in[14];
    const float* PW1   = (const float*)d_in[15];
    const float* Pb1   = (const float*)d_in[16];
    const float* PW2   = (const float*)d_in[17];
    const float* Pb2   = (const float*)d_in[18];

    // ws layout (elements)
    const size_t SZ_STATE = (size_t)B_TOTAL * F_IN;
    const size_t SZ_W00   = (size_t)U_UNITS * HID * F_IN;
    const size_t SZ_W01   = (size_t)U_UNITS * HID * U_UNITS;
    const size_t NEED = (2 * SZ_STATE + 2 * SZ_W00 + 2 * SZ_W01
                         + (size_t)B_TOTAL * U_UNITS) * 2            // fp16 parts + a0
                        + (size_t)U_UNITS * B_TOTAL * 4;             // a1T fp32

    if (ws_size >= NEED) {
        char* p = (char*)d_ws;
        _Float16* state_h = (_Float16*)p;                p += SZ_STATE * 2;
        _Float16* state_l = (_Float16*)p;                p += SZ_STATE * 2;
        _Float16* w00_h   = (_Float16*)p;                p += SZ_W00 * 2;
        _Float16* w00_l   = (_Float16*)p;                p += SZ_W00 * 2;
        _Float16* w01_h   = (_Float16*)p;                p += SZ_W01 * 2;
        _Float16* w01_l   = (_Float16*)p;                p += SZ_W01 * 2;
        _Float16* a0      = (_Float16*)p;                p += (size_t)B_TOTAL * U_UNITS * 2;
        float*    a1T     = (float*)p;

        // fused pack: fp32 -> fragment-ordered fp16 (h, l*2048), one launch
        constexpr int NB0 = (B_TOTAL / 16) * (F_IN / 128);
        constexpr int NB1 = (U_UNITS * HID / 16) * (F_IN / 128);
        constexpr int NB2 = (U_UNITS * HID / 16) * (U_UNITS / 128);
        pack3_kernel<<<NB0 + NB1 + NB2, 256, 0, stream>>>(
            state, state_h, state_l, W0_0, w00_h, w00_l, W0_1, w01_h, w01_l);

        dim3 grid((U_UNITS * HID) / BN, B_TOTAL / BM);   // (16, 64)

        coagent_mfma<F_IN, true, false><<<grid, 256, 0, stream>>>(
            state_h, state_l, w00_h, w00_l, b0_0, W1_0, b1_0, W2_0, b2_0, (void*)a0);

        coagent_mfma<U_UNITS, false, true><<<grid, 256, 0, stream>>>(
            a0, nullptr, w01_h, w01_l, b0_1, W1_1, b1_1, W2_1, b2_1, (void*)a1T);

        policy_kernel<<<B_TOTAL / 32, 256, 0, stream>>>(
            a1T, PW0, Pb0, PW1, Pb1, PW2, Pb2, (float*)d_out);
    } else {
        // fp32 fallback (round-1 path, needs 16 MB ws)
        float* a0T = (float*)d_ws;
        float* a1T = a0T + (size_t)U_UNITS * B_TOTAL;
        dim3 grid((U_UNITS * HID) / FBN, B_TOTAL / FBM);
        coagent_kernel<F_IN, false><<<grid, 256, 0, stream>>>(
            state, W0_0, b0_0, W1_0, b1_0, W2_0, b2_0, a0T);
        coagent_kernel<U_UNITS, true><<<grid, 256, 0, stream>>>(
            a0T, W0_1, b0_1, W1_1, b1_1, W2_1, b2_1, a1T);
        // fallback policy path: same u-sliced kernel works on a1T [U][B]
        policy_kernel<<<B_TOTAL / 32, 256, 0, stream>>>(
            a1T, PW0, Pb0, PW1, Pb1, PW2, Pb2, (float*)d_out);
    }
}